// Round 1
// baseline (305.405 us; speedup 1.0000x reference)
//
#include <hip/hip_runtime.h>
#include <cstddef>

#define BB  32
#define CC  128
#define HH  64
#define WW  64
#define OO  256
#define OHH 32
#define OWW 32

// Transform weight [O][C][3][3] -> wt[(c*9+k)*256 + o] so the main kernel can
// do perfectly coalesced float4 weight loads per (c,k).
__global__ void wtrans_kernel(const float* __restrict__ w, float* __restrict__ wt) {
    int idx = blockIdx.x * 256 + threadIdx.x;
    if (idx >= CC * 9 * OO) return;
    int o  = idx & (OO - 1);
    int ck = idx >> 8;            // c*9 + k
    int c  = ck / 9;
    int k  = ck - c * 9;
    wt[idx] = w[((size_t)o * CC + c) * 9 + k];
}

template <bool TRANS>
__global__ __launch_bounds__(256)
void conv_kernel(const float* __restrict__ x, const float* __restrict__ w,
                 const float* __restrict__ bias, const float* __restrict__ shp,
                 const float* __restrict__ swp, float* __restrict__ out) {
    __shared__ __align__(16) float xr[4][WW];       // 4 staged input rows
    __shared__ __align__(16) float patch[9][OWW];   // interpolated im2col [k][q]

    const int tid = threadIdx.x;
    const int p = blockIdx.x;
    const int b = blockIdx.y;
    const float sh = shp[0];
    const float sw = swp[0];

    // Row geometry for this output row p: rows hb..hb+3, frac fh (same for all kh)
    const float hpos = (float)p * sh - 1.0f;
    const float hbf  = floorf(hpos);
    const float fh   = hpos - hbf;
    const int   hb   = (int)hbf;

    // MAC-loop ownership: 4 consecutive o, 8 consecutive q per thread.
    const int og = tid & 63;   // o-group: wave-lane
    const int qg = tid >> 6;   // q-group: wave index (wave-uniform -> LDS broadcast)
    const int o0 = og * 4;
    const int q0 = qg * 8;

    // Staging ownership: one (row, col) per thread, coalesced 64-wide.
    const int rr   = tid >> 6;
    const int colc = tid & 63;
    const int rowg = hb + rr;
    const bool rvalid = (rowg >= 0) && (rowg < HH);

    float acc[4][8];
#pragma unroll
    for (int i = 0; i < 4; ++i)
#pragma unroll
        for (int j = 0; j < 8; ++j) acc[i][j] = 0.0f;

    for (int c = 0; c < CC; ++c) {
        // ---- stage 4 rows of x[b][c] ----
        float v = 0.0f;
        if (rvalid) v = x[(((size_t)b * CC + c) * HH + rowg) * WW + colc];
        xr[rr][colc] = v;
        __syncthreads();

        // ---- build interpolated patch[9][32] ----
        for (int it = tid; it < 9 * OWW; it += 256) {
            int k = it >> 5;
            int q = it & 31;
            int kh = k / 3;
            int kw = k - kh * 3;
            float wpos = (float)q * sw - 1.0f + (float)kw;
            float wbf = floorf(wpos);
            float fw = wpos - wbf;
            int wb = (int)wbf;
            float x00 = 0.0f, x01 = 0.0f, x10 = 0.0f, x11 = 0.0f;
            if (wb >= 0 && wb < WW)           { x00 = xr[kh][wb];     x10 = xr[kh + 1][wb]; }
            if (wb + 1 >= 0 && wb + 1 < WW)   { x01 = xr[kh][wb + 1]; x11 = xr[kh + 1][wb + 1]; }
            float top = x00 * (1.0f - fw) + x01 * fw;
            float bot = x10 * (1.0f - fw) + x11 * fw;
            patch[k][q] = top * (1.0f - fh) + bot * fh;
        }
        __syncthreads();

        // ---- MAC: 9 taps x 4 o x 8 q ----
        const float4* pv = (const float4*)&patch[0][0];  // [9][8] float4
#pragma unroll
        for (int k = 0; k < 9; ++k) {
            float4 wv;
            if (TRANS) {
                wv = ((const float4*)(w + ((size_t)c * 9 + k) * OO))[og];
            } else {
                const float* wb_ = w + (size_t)o0 * (CC * 9) + c * 9 + k;
                wv.x = wb_[0];
                wv.y = wb_[1 * CC * 9];
                wv.z = wb_[2 * CC * 9];
                wv.w = wb_[3 * CC * 9];
            }
            float4 pa = pv[k * 8 + (q0 >> 2)];
            float4 pb = pv[k * 8 + (q0 >> 2) + 1];
            float wvv[4] = {wv.x, wv.y, wv.z, wv.w};
#pragma unroll
            for (int oo2 = 0; oo2 < 4; ++oo2) {
                acc[oo2][0] += wvv[oo2] * pa.x;
                acc[oo2][1] += wvv[oo2] * pa.y;
                acc[oo2][2] += wvv[oo2] * pa.z;
                acc[oo2][3] += wvv[oo2] * pa.w;
                acc[oo2][4] += wvv[oo2] * pb.x;
                acc[oo2][5] += wvv[oo2] * pb.y;
                acc[oo2][6] += wvv[oo2] * pb.z;
                acc[oo2][7] += wvv[oo2] * pb.w;
            }
        }
        // no barrier needed here: next-iter stores are fenced by the two barriers above
    }

    // ---- epilogue: + bias, store ----
    float4 bv = ((const float4*)bias)[og];
    float bvv[4] = {bv.x, bv.y, bv.z, bv.w};
#pragma unroll
    for (int oo2 = 0; oo2 < 4; ++oo2) {
        size_t off = (((size_t)b * OO + o0 + oo2) * OHH + p) * OWW + q0;
        float4 r0, r1;
        r0.x = acc[oo2][0] + bvv[oo2];
        r0.y = acc[oo2][1] + bvv[oo2];
        r0.z = acc[oo2][2] + bvv[oo2];
        r0.w = acc[oo2][3] + bvv[oo2];
        r1.x = acc[oo2][4] + bvv[oo2];
        r1.y = acc[oo2][5] + bvv[oo2];
        r1.z = acc[oo2][6] + bvv[oo2];
        r1.w = acc[oo2][7] + bvv[oo2];
        *(float4*)(out + off)     = r0;
        *(float4*)(out + off + 4) = r1;
    }
}

extern "C" void kernel_launch(void* const* d_in, const int* in_sizes, int n_in,
                              void* d_out, int out_size, void* d_ws, size_t ws_size,
                              hipStream_t stream) {
    const float* x    = (const float*)d_in[0];
    const float* w    = (const float*)d_in[1];
    const float* bias = (const float*)d_in[2];
    const float* shp  = (const float*)d_in[3];
    const float* swp  = (const float*)d_in[4];
    float* out = (float*)d_out;

    const size_t wt_bytes = (size_t)CC * 9 * OO * sizeof(float);
    dim3 grid(OHH, BB);
    if (ws_size >= wt_bytes) {
        float* wt = (float*)d_ws;
        int n = CC * 9 * OO;
        wtrans_kernel<<<(n + 255) / 256, 256, 0, stream>>>(w, wt);
        conv_kernel<true><<<grid, 256, 0, stream>>>(x, wt, bias, shp, swp, out);
    } else {
        conv_kernel<false><<<grid, 256, 0, stream>>>(x, w, bias, shp, swp, out);
    }
}

// Round 2
// 128.469 us; speedup vs baseline: 2.3773x; 2.3773x over previous
//
#include <hip/hip_runtime.h>
#include <cstddef>

#define BB  32
#define CC  128
#define HH  64
#define WW  64
#define OO  256
#define OHH 32
#define OWW 32

typedef __bf16 bf16x8 __attribute__((ext_vector_type(8)));
typedef float  f32x4  __attribute__((ext_vector_type(4)));

// ---- weight transform: w[o][c][3][3] f32  ->  wt[o][k][c] bf16 (k = kh*3+kw) ----
__global__ void wtrans_bf16_kernel(const float* __restrict__ w, __bf16* __restrict__ wt) {
    int idx = blockIdx.x * 256 + threadIdx.x;          // idx = (o*9 + k)*128 + c
    if (idx >= OO * 9 * CC) return;
    int c    = idx & 127;
    int rest = idx >> 7;
    int k    = rest % 9;
    int o    = rest / 9;
    wt[idx] = (__bf16)w[((size_t)o * CC + c) * 9 + k];
}

// ---- main fused im2col(bilinear) + bf16 MFMA GEMM ----
// grid (p=32, b=32), 256 threads = 4 waves. Wave w: o in [64w, 64w+64), q 0..31.
__global__ __launch_bounds__(256)
void conv_mfma_kernel(const float* __restrict__ x, const __bf16* __restrict__ wt,
                      const float* __restrict__ bias, const float* __restrict__ shp,
                      const float* __restrict__ swp, float* __restrict__ out) {
    // yr: row-interpolated input, [c(32)][kh(3)][w(64)] f32, c-stride 193 (conflict-free)
    __shared__ float  yr[32 * 193];                    // 24.7 KB
    // patchT: bf16 B-operand, [k(9)][q(32)][c(40 pad)]  (pad 40 -> <=2-way on b128 reads)
    __shared__ __bf16 patchT[9 * 32 * 40];             // 23 KB

    const int tid = threadIdx.x;
    const int p   = blockIdx.x;
    const int b   = blockIdx.y;
    const float sh = shp[0];
    const float sw = swp[0];

    const float hpos = (float)p * sh - 1.0f;
    const float hbf  = floorf(hpos);
    const float fh   = hpos - hbf;
    const int   hb   = (int)hbf;

    // ---- bias-only fast path: all 4 sampled rows out of range -> patch == 0 ----
    if (hb >= HH || hb <= -4) {
        int o = tid;
        float bv = bias[o];
        float4 r; r.x = bv; r.y = bv; r.z = bv; r.w = bv;
        float* op = out + (((size_t)b * OO + o) * OHH + p) * OWW;
#pragma unroll
        for (int j = 0; j < 8; ++j) *(float4*)(op + j * 4) = r;
        return;
    }

    const int wv = tid >> 6;     // wave id -> o block
    const int l  = tid & 63;
    const int lr = l & 15;       // A row / B col within tile
    const int lg = l >> 4;       // k-group (8 elems each)
    const int o0 = wv * 64;

    // row validity for staging
    int   hr[4];
    float rvalid[4];
#pragma unroll
    for (int r = 0; r < 4; ++r) {
        hr[r] = hb + r;
        rvalid[r] = (hr[r] >= 0 && hr[r] < HH) ? 1.0f : 0.0f;
    }

    f32x4 acc[4][2];
#pragma unroll
    for (int ot = 0; ot < 4; ++ot)
#pragma unroll
        for (int qt = 0; qt < 2; ++qt) acc[ot][qt] = (f32x4)0.0f;

    for (int chunk = 0; chunk < 4; ++chunk) {
        const int c0 = chunk * 32;

        // ---- stage A: global x -> row-interp yr (f32) ----
#pragma unroll
        for (int i = 0; i < 2; ++i) {
            int idx  = tid + i * 256;          // < 512
            int c    = idx >> 4;               // 0..31
            int col4 = (idx & 15) << 2;        // 0..60
            const float* xp = x + (((size_t)b * CC + c0 + c) * HH) * WW + col4;
            float4 v[4];
#pragma unroll
            for (int r = 0; r < 4; ++r) {
                float4 t = {0.f, 0.f, 0.f, 0.f};
                if (rvalid[r] > 0.f) t = *(const float4*)(xp + (size_t)hr[r] * WW);
                v[r] = t;
            }
            float* yb = &yr[c * 193 + col4];
#pragma unroll
            for (int kh = 0; kh < 3; ++kh) {
                float4 y;
                y.x = v[kh].x + fh * (v[kh + 1].x - v[kh].x);
                y.y = v[kh].y + fh * (v[kh + 1].y - v[kh].y);
                y.z = v[kh].z + fh * (v[kh + 1].z - v[kh].z);
                y.w = v[kh].w + fh * (v[kh + 1].w - v[kh].w);
                yb[kh * 64 + 0] = y.x;
                yb[kh * 64 + 1] = y.y;
                yb[kh * 64 + 2] = y.z;
                yb[kh * 64 + 3] = y.w;
            }
        }
        __syncthreads();

        // ---- stage B: col-interp -> patchT (bf16) ----
#pragma unroll 4
        for (int it = 0; it < 36; ++it) {
            int idx = tid + it * 256;          // = k*1024 + q*32 + c
            int c   = idx & 31;
            int q   = (idx >> 5) & 31;
            int k   = idx >> 10;               // 0..8
            int kh  = k / 3;
            int kw  = k - 3 * kh;
            float wpos = (float)q * sw - 1.0f + (float)kw;
            float wbf  = floorf(wpos);
            float fw   = wpos - wbf;
            int   wb   = (int)wbf;
            const float* yb = &yr[c * 193 + kh * 64];
            float a = (wb >= 0 && wb < WW)         ? yb[wb]     : 0.0f;
            float d = (wb + 1 >= 0 && wb + 1 < WW) ? yb[wb + 1] : 0.0f;
            patchT[(k * 32 + q) * 40 + c] = (__bf16)(a + fw * (d - a));
        }
        __syncthreads();

        // ---- MFMA: 9 K-slices of 32 (one tap k x 32 channels) ----
        for (int k = 0; k < 9; ++k) {
            const __bf16* wp = wt + ((size_t)(o0 + lr) * 9 + k) * CC + c0 + lg * 8;
            bf16x8 a0 = *(const bf16x8*)(wp + (size_t)0  * 9 * CC);
            bf16x8 a1 = *(const bf16x8*)(wp + (size_t)16 * 9 * CC);
            bf16x8 a2 = *(const bf16x8*)(wp + (size_t)32 * 9 * CC);
            bf16x8 a3 = *(const bf16x8*)(wp + (size_t)48 * 9 * CC);
            bf16x8 b0 = *(const bf16x8*)&patchT[(k * 32 + lr) * 40 + lg * 8];
            bf16x8 b1 = *(const bf16x8*)&patchT[(k * 32 + 16 + lr) * 40 + lg * 8];
            acc[0][0] = __builtin_amdgcn_mfma_f32_16x16x32_bf16(a0, b0, acc[0][0], 0, 0, 0);
            acc[0][1] = __builtin_amdgcn_mfma_f32_16x16x32_bf16(a0, b1, acc[0][1], 0, 0, 0);
            acc[1][0] = __builtin_amdgcn_mfma_f32_16x16x32_bf16(a1, b0, acc[1][0], 0, 0, 0);
            acc[1][1] = __builtin_amdgcn_mfma_f32_16x16x32_bf16(a1, b1, acc[1][1], 0, 0, 0);
            acc[2][0] = __builtin_amdgcn_mfma_f32_16x16x32_bf16(a2, b0, acc[2][0], 0, 0, 0);
            acc[2][1] = __builtin_amdgcn_mfma_f32_16x16x32_bf16(a2, b1, acc[2][1], 0, 0, 0);
            acc[3][0] = __builtin_amdgcn_mfma_f32_16x16x32_bf16(a3, b0, acc[3][0], 0, 0, 0);
            acc[3][1] = __builtin_amdgcn_mfma_f32_16x16x32_bf16(a3, b1, acc[3][1], 0, 0, 0);
        }
        __syncthreads();
    }

    // ---- epilogue: + bias, store (C/D layout: col=lane&15, row=(lane>>4)*4+reg) ----
#pragma unroll
    for (int ot = 0; ot < 4; ++ot) {
#pragma unroll
        for (int r = 0; r < 4; ++r) {
            int o = o0 + ot * 16 + lg * 4 + r;
            float bv = bias[o];
            float* op = out + (((size_t)b * OO + o) * OHH + p) * OWW;
            op[lr]      = acc[ot][0][r] + bv;
            op[16 + lr] = acc[ot][1][r] + bv;
        }
    }
}

// ---- fp32 fallback (no workspace needed) — previous round's kernel ----
__global__ __launch_bounds__(256)
void conv_fallback_kernel(const float* __restrict__ x, const float* __restrict__ w,
                          const float* __restrict__ bias, const float* __restrict__ shp,
                          const float* __restrict__ swp, float* __restrict__ out) {
    __shared__ __align__(16) float xr[4][WW];
    __shared__ __align__(16) float patch[9][OWW];
    const int tid = threadIdx.x;
    const int p = blockIdx.x;
    const int b = blockIdx.y;
    const float sh = shp[0];
    const float sw = swp[0];
    const float hpos = (float)p * sh - 1.0f;
    const float hbf  = floorf(hpos);
    const float fh   = hpos - hbf;
    const int   hb   = (int)hbf;
    const int og = tid & 63;
    const int qg = tid >> 6;
    const int o0 = og * 4;
    const int q0 = qg * 8;
    const int rr   = tid >> 6;
    const int colc = tid & 63;
    const int rowg = hb + rr;
    const bool rv = (rowg >= 0) && (rowg < HH);
    float acc[4][8];
#pragma unroll
    for (int i = 0; i < 4; ++i)
#pragma unroll
        for (int j = 0; j < 8; ++j) acc[i][j] = 0.0f;
    for (int c = 0; c < CC; ++c) {
        float v = 0.0f;
        if (rv) v = x[(((size_t)b * CC + c) * HH + rowg) * WW + colc];
        xr[rr][colc] = v;
        __syncthreads();
        for (int it = tid; it < 9 * OWW; it += 256) {
            int k = it >> 5; int q = it & 31;
            int kh = k / 3;  int kw = k - kh * 3;
            float wpos = (float)q * sw - 1.0f + (float)kw;
            float wbf = floorf(wpos);
            float fw = wpos - wbf;
            int wb = (int)wbf;
            float x00 = 0, x01 = 0, x10 = 0, x11 = 0;
            if (wb >= 0 && wb < WW)         { x00 = xr[kh][wb];     x10 = xr[kh + 1][wb]; }
            if (wb + 1 >= 0 && wb + 1 < WW) { x01 = xr[kh][wb + 1]; x11 = xr[kh + 1][wb + 1]; }
            float top = x00 * (1.0f - fw) + x01 * fw;
            float bot = x10 * (1.0f - fw) + x11 * fw;
            patch[k][q] = top * (1.0f - fh) + bot * fh;
        }
        __syncthreads();
        const float4* pv = (const float4*)&patch[0][0];
#pragma unroll
        for (int k = 0; k < 9; ++k) {
            const float* wb_ = w + (size_t)o0 * (CC * 9) + c * 9 + k;
            float wvv[4] = {wb_[0], wb_[1 * CC * 9], wb_[2 * CC * 9], wb_[3 * CC * 9]};
            float4 pa = pv[k * 8 + (q0 >> 2)];
            float4 pb = pv[k * 8 + (q0 >> 2) + 1];
#pragma unroll
            for (int oo2 = 0; oo2 < 4; ++oo2) {
                acc[oo2][0] += wvv[oo2] * pa.x; acc[oo2][1] += wvv[oo2] * pa.y;
                acc[oo2][2] += wvv[oo2] * pa.z; acc[oo2][3] += wvv[oo2] * pa.w;
                acc[oo2][4] += wvv[oo2] * pb.x; acc[oo2][5] += wvv[oo2] * pb.y;
                acc[oo2][6] += wvv[oo2] * pb.z; acc[oo2][7] += wvv[oo2] * pb.w;
            }
        }
    }
    float4 bv = ((const float4*)bias)[og];
    float bvv[4] = {bv.x, bv.y, bv.z, bv.w};
#pragma unroll
    for (int oo2 = 0; oo2 < 4; ++oo2) {
        size_t off = (((size_t)b * OO + o0 + oo2) * OHH + p) * OWW + q0;
        float4 r0, r1;
        r0.x = acc[oo2][0] + bvv[oo2]; r0.y = acc[oo2][1] + bvv[oo2];
        r0.z = acc[oo2][2] + bvv[oo2]; r0.w = acc[oo2][3] + bvv[oo2];
        r1.x = acc[oo2][4] + bvv[oo2]; r1.y = acc[oo2][5] + bvv[oo2];
        r1.z = acc[oo2][6] + bvv[oo2]; r1.w = acc[oo2][7] + bvv[oo2];
        *(float4*)(out + off)     = r0;
        *(float4*)(out + off + 4) = r1;
    }
}

extern "C" void kernel_launch(void* const* d_in, const int* in_sizes, int n_in,
                              void* d_out, int out_size, void* d_ws, size_t ws_size,
                              hipStream_t stream) {
    const float* x    = (const float*)d_in[0];
    const float* w    = (const float*)d_in[1];
    const float* bias = (const float*)d_in[2];
    const float* shp  = (const float*)d_in[3];
    const float* swp  = (const float*)d_in[4];
    float* out = (float*)d_out;

    const size_t wt_bytes = (size_t)OO * 9 * CC * sizeof(__bf16);   // 576 KB
    dim3 grid(OHH, BB);
    if (ws_size >= wt_bytes) {
        __bf16* wt = (__bf16*)d_ws;
        int n = OO * 9 * CC;
        wtrans_bf16_kernel<<<(n + 255) / 256, 256, 0, stream>>>(w, wt);
        conv_mfma_kernel<<<grid, 256, 0, stream>>>(x, wt, bias, shp, swp, out);
    } else {
        conv_fallback_kernel<<<grid, 256, 0, stream>>>(x, w, bias, shp, swp, out);
    }
}

// Round 3
// 94.756 us; speedup vs baseline: 3.2231x; 1.3558x over previous
//
#include <hip/hip_runtime.h>
#include <cstddef>

#define BB  32
#define CC  128
#define HH  64
#define WW  64
#define OO  256
#define OHH 32
#define OWW 32
#define YSTR 196   // bf16 elems; 392B row: 8B-aligned, <=2-way banks

typedef __bf16 bf16x8 __attribute__((ext_vector_type(8)));
typedef __bf16 bf16x4 __attribute__((ext_vector_type(4)));
typedef float  f32x4  __attribute__((ext_vector_type(4)));

// ---- weight transform: w[o][c][3][3] f32 -> wt[o][k][c] bf16 (k = kh*3+kw) ----
__global__ void wtrans_bf16_kernel(const float* __restrict__ w, __bf16* __restrict__ wt) {
    int idx = blockIdx.x * 256 + threadIdx.x;          // (o*9 + k)*128 + c
    if (idx >= OO * 9 * CC) return;
    int c    = idx & 127;
    int rest = idx >> 7;
    int k    = rest % 9;
    int o    = rest / 9;
    wt[idx] = (__bf16)w[((size_t)o * CC + c) * 9 + k];
}

// ---- fused bilinear-im2col + bf16 MFMA; grid (p=32,b=32), 256 thr = 4 waves ----
__global__ __launch_bounds__(256, 4)
void conv_mfma_kernel(const float* __restrict__ x, const __bf16* __restrict__ wt,
                      const float* __restrict__ bias, const float* __restrict__ shp,
                      const float* __restrict__ swp, float* __restrict__ out) {
    __shared__ __bf16 yr[32 * YSTR];          // 12.25 KB row-interp (bf16)
    __shared__ __bf16 patchT[9 * 32 * 40];    // 22.5 KB B-operand [k][q][c+pad]
    __shared__ float  fwtab[OWW];
    __shared__ int    wbtab[OWW];

    const int tid = threadIdx.x;
    const int p   = blockIdx.x;
    const int b   = blockIdx.y;
    const float sh = shp[0];
    const float sw = swp[0];

    const float hpos = (float)p * sh - 1.0f;
    const float hbf  = floorf(hpos);
    const float fh   = hpos - hbf;
    const int   hb   = (int)hbf;

    // ---- bias-only fast path (rows fully OOB) ----
    if (hb >= HH || hb <= -4) {
#pragma unroll
        for (int rep = 0; rep < 8; ++rep) {
            int o  = rep * 32 + (tid >> 3);
            int q0 = (tid & 7) << 2;
            float bv = bias[o];
            float4 r; r.x = bv; r.y = bv; r.z = bv; r.w = bv;
            *(float4*)(out + (((size_t)b * OO + o) * OHH + p) * OWW + q0) = r;
        }
        return;
    }

    // per-q column geometry table (computed once, reused all chunks)
    if (tid < OWW) {
        float wpos = (float)tid * sw - 1.0f;
        float wbf  = floorf(wpos);
        fwtab[tid] = wpos - wbf;
        wbtab[tid] = (int)wbf;
    }

    const int wv = tid >> 6;     // wave -> o block
    const int l  = tid & 63;
    const int lr = l & 15;
    const int lg = l >> 4;
    const int o0 = wv * 64;

    int  hr[4];
    bool rvb[4];
#pragma unroll
    for (int r = 0; r < 4; ++r) {
        hr[r]  = hb + r;
        rvb[r] = (hr[r] >= 0) && (hr[r] < HH);
    }

    // staging ownership: c = cA (+16 for i=1), 4 consecutive cols
    const int cA   = tid >> 4;            // 0..15
    const int col4 = (tid & 15) << 2;     // 0..60

    f32x4 acc[4][2];
#pragma unroll
    for (int ot = 0; ot < 4; ++ot)
#pragma unroll
        for (int qt = 0; qt < 2; ++qt) acc[ot][qt] = (f32x4)0.0f;

    float4 v[2][4];
    // prefetch chunk 0
#pragma unroll
    for (int i = 0; i < 2; ++i) {
        const float* xp = x + ((size_t)(b * CC + cA + i * 16) * HH) * WW + col4;
#pragma unroll
        for (int r = 0; r < 4; ++r) {
            float4 t = {0.f, 0.f, 0.f, 0.f};
            if (rvb[r]) t = *(const float4*)(xp + (size_t)hr[r] * WW);
            v[i][r] = t;
        }
    }

    for (int chunk = 0; chunk < 4; ++chunk) {
        const int c0 = chunk * 32;

        // ---- yr-write: row interp from prefetched regs ----
#pragma unroll
        for (int i = 0; i < 2; ++i) {
            __bf16* yb = &yr[(cA + i * 16) * YSTR + col4];
#pragma unroll
            for (int kh = 0; kh < 3; ++kh) {
                float4 a = v[i][kh], d = v[i][kh + 1];
                bf16x4 t;
                t[0] = (__bf16)(a.x + fh * (d.x - a.x));
                t[1] = (__bf16)(a.y + fh * (d.y - a.y));
                t[2] = (__bf16)(a.z + fh * (d.z - a.z));
                t[3] = (__bf16)(a.w + fh * (d.w - a.w));
                *(bf16x4*)(yb + kh * 64) = t;
            }
        }
        __syncthreads();   // barA: yr + qtab ready; prev MFMA's LDS reads drained

        // ---- prefetch next chunk (latency hides under stage B, drains at barB) ----
        if (chunk < 3) {
#pragma unroll
            for (int i = 0; i < 2; ++i) {
                const float* xp = x + ((size_t)(b * CC + c0 + 32 + cA + i * 16) * HH) * WW + col4;
#pragma unroll
                for (int r = 0; r < 4; ++r) {
                    float4 t = {0.f, 0.f, 0.f, 0.f};
                    if (rvb[r]) t = *(const float4*)(xp + (size_t)hr[r] * WW);
                    v[i][r] = t;
                }
            }
        }

        // ---- stage B: col interp yr -> patchT ----
#pragma unroll 4
        for (int it = 0; it < 36; ++it) {
            int idx = tid + it * 256;          // k*1024 + q*32 + c
            int c   = idx & 31;
            int q   = (idx >> 5) & 31;
            int k   = idx >> 10;
            int kh  = k / 3;
            int kw  = k - 3 * kh;
            float fw = fwtab[q];
            int   wb = wbtab[q] + kw;
            const __bf16* yb = &yr[c * YSTR + kh * 64];
            float a = ((unsigned)wb < WW)       ? (float)yb[wb]     : 0.0f;
            float d = ((unsigned)(wb + 1) < WW) ? (float)yb[wb + 1] : 0.0f;
            patchT[(k * 32 + q) * 40 + c] = (__bf16)(a + fw * (d - a));
        }
        __syncthreads();   // barB: patchT ready; yr reads + x prefetch drained

        // ---- MFMA: 9 taps x (4o x 2q) tiles ----
        __builtin_amdgcn_s_setprio(1);
#pragma unroll
        for (int k = 0; k < 9; ++k) {
            const __bf16* wp = wt + ((size_t)(o0 + lr) * 9 + k) * CC + c0 + lg * 8;
            bf16x8 a0 = *(const bf16x8*)(wp + (size_t)0  * 9 * CC);
            bf16x8 a1 = *(const bf16x8*)(wp + (size_t)16 * 9 * CC);
            bf16x8 a2 = *(const bf16x8*)(wp + (size_t)32 * 9 * CC);
            bf16x8 a3 = *(const bf16x8*)(wp + (size_t)48 * 9 * CC);
            bf16x8 b0 = *(const bf16x8*)&patchT[(k * 32 + lr) * 40 + lg * 8];
            bf16x8 b1 = *(const bf16x8*)&patchT[(k * 32 + 16 + lr) * 40 + lg * 8];
            acc[0][0] = __builtin_amdgcn_mfma_f32_16x16x32_bf16(a0, b0, acc[0][0], 0, 0, 0);
            acc[0][1] = __builtin_amdgcn_mfma_f32_16x16x32_bf16(a0, b1, acc[0][1], 0, 0, 0);
            acc[1][0] = __builtin_amdgcn_mfma_f32_16x16x32_bf16(a1, b0, acc[1][0], 0, 0, 0);
            acc[1][1] = __builtin_amdgcn_mfma_f32_16x16x32_bf16(a1, b1, acc[1][1], 0, 0, 0);
            acc[2][0] = __builtin_amdgcn_mfma_f32_16x16x32_bf16(a2, b0, acc[2][0], 0, 0, 0);
            acc[2][1] = __builtin_amdgcn_mfma_f32_16x16x32_bf16(a2, b1, acc[2][1], 0, 0, 0);
            acc[3][0] = __builtin_amdgcn_mfma_f32_16x16x32_bf16(a3, b0, acc[3][0], 0, 0, 0);
            acc[3][1] = __builtin_amdgcn_mfma_f32_16x16x32_bf16(a3, b1, acc[3][1], 0, 0, 0);
        }
        __builtin_amdgcn_s_setprio(0);
        // no trailing barrier: yr-write (next iter) only conflicts with stage-B
        // reads (fenced by barB); patchT overwrite fenced by next barA.
    }

    // ---- epilogue: + bias, store (C/D: col=lane&15, row=(lane>>4)*4+reg) ----
#pragma unroll
    for (int ot = 0; ot < 4; ++ot) {
#pragma unroll
        for (int r = 0; r < 4; ++r) {
            int o = o0 + ot * 16 + lg * 4 + r;
            float bv = bias[o];
            float* op = out + (((size_t)b * OO + o) * OHH + p) * OWW;
            op[lr]      = acc[ot][0][r] + bv;
            op[16 + lr] = acc[ot][1][r] + bv;
        }
    }
}

// ---- fp32 fallback (no workspace) ----
__global__ __launch_bounds__(256)
void conv_fallback_kernel(const float* __restrict__ x, const float* __restrict__ w,
                          const float* __restrict__ bias, const float* __restrict__ shp,
                          const float* __restrict__ swp, float* __restrict__ out) {
    __shared__ __align__(16) float xr[4][WW];
    __shared__ __align__(16) float patch[9][OWW];
    const int tid = threadIdx.x;
    const int p = blockIdx.x;
    const int b = blockIdx.y;
    const float sh = shp[0];
    const float sw = swp[0];
    const float hpos = (float)p * sh - 1.0f;
    const float hbf  = floorf(hpos);
    const float fh   = hpos - hbf;
    const int   hb   = (int)hbf;
    const int og = tid & 63;
    const int qg = tid >> 6;
    const int o0 = og * 4;
    const int q0 = qg * 8;
    const int rr   = tid >> 6;
    const int colc = tid & 63;
    const int rowg = hb + rr;
    const bool rv = (rowg >= 0) && (rowg < HH);
    float acc[4][8];
#pragma unroll
    for (int i = 0; i < 4; ++i)
#pragma unroll
        for (int j = 0; j < 8; ++j) acc[i][j] = 0.0f;
    for (int c = 0; c < CC; ++c) {
        float vv = 0.0f;
        if (rv) vv = x[(((size_t)b * CC + c) * HH + rowg) * WW + colc];
        xr[rr][colc] = vv;
        __syncthreads();
        for (int it = tid; it < 9 * OWW; it += 256) {
            int k = it >> 5; int q = it & 31;
            int kh = k / 3;  int kw = k - kh * 3;
            float wpos = (float)q * sw - 1.0f + (float)kw;
            float wbf = floorf(wpos);
            float fw = wpos - wbf;
            int wb = (int)wbf;
            float x00 = 0, x01 = 0, x10 = 0, x11 = 0;
            if (wb >= 0 && wb < WW)         { x00 = xr[kh][wb];     x10 = xr[kh + 1][wb]; }
            if (wb + 1 >= 0 && wb + 1 < WW) { x01 = xr[kh][wb + 1]; x11 = xr[kh + 1][wb + 1]; }
            float top = x00 * (1.0f - fw) + x01 * fw;
            float bot = x10 * (1.0f - fw) + x11 * fw;
            patch[k][q] = top * (1.0f - fh) + bot * fh;
        }
        __syncthreads();
        const float4* pv = (const float4*)&patch[0][0];
#pragma unroll
        for (int k = 0; k < 9; ++k) {
            const float* wb_ = w + (size_t)o0 * (CC * 9) + c * 9 + k;
            float wvv[4] = {wb_[0], wb_[1 * CC * 9], wb_[2 * CC * 9], wb_[3 * CC * 9]};
            float4 pa = pv[k * 8 + (q0 >> 2)];
            float4 pb = pv[k * 8 + (q0 >> 2) + 1];
#pragma unroll
            for (int oo2 = 0; oo2 < 4; ++oo2) {
                acc[oo2][0] += wvv[oo2] * pa.x; acc[oo2][1] += wvv[oo2] * pa.y;
                acc[oo2][2] += wvv[oo2] * pa.z; acc[oo2][3] += wvv[oo2] * pa.w;
                acc[oo2][4] += wvv[oo2] * pb.x; acc[oo2][5] += wvv[oo2] * pb.y;
                acc[oo2][6] += wvv[oo2] * pb.z; acc[oo2][7] += wvv[oo2] * pb.w;
            }
        }
    }
    float4 bv = ((const float4*)bias)[og];
    float bvv[4] = {bv.x, bv.y, bv.z, bv.w};
#pragma unroll
    for (int oo2 = 0; oo2 < 4; ++oo2) {
        size_t off = (((size_t)b * OO + o0 + oo2) * OHH + p) * OWW + q0;
        float4 r0, r1;
        r0.x = acc[oo2][0] + bvv[oo2]; r0.y = acc[oo2][1] + bvv[oo2];
        r0.z = acc[oo2][2] + bvv[oo2]; r0.w = acc[oo2][3] + bvv[oo2];
        r1.x = acc[oo2][4] + bvv[oo2]; r1.y = acc[oo2][5] + bvv[oo2];
        r1.z = acc[oo2][6] + bvv[oo2]; r1.w = acc[oo2][7] + bvv[oo2];
        *(float4*)(out + off)     = r0;
        *(float4*)(out + off + 4) = r1;
    }
}

extern "C" void kernel_launch(void* const* d_in, const int* in_sizes, int n_in,
                              void* d_out, int out_size, void* d_ws, size_t ws_size,
                              hipStream_t stream) {
    const float* x    = (const float*)d_in[0];
    const float* w    = (const float*)d_in[1];
    const float* bias = (const float*)d_in[2];
    const float* shp  = (const float*)d_in[3];
    const float* swp  = (const float*)d_in[4];
    float* out = (float*)d_out;

    const size_t wt_bytes = (size_t)OO * 9 * CC * sizeof(__bf16);   // 576 KB
    dim3 grid(OHH, BB);
    if (ws_size >= wt_bytes) {
        __bf16* wtp = (__bf16*)d_ws;
        int n = OO * 9 * CC;
        wtrans_bf16_kernel<<<(n + 255) / 256, 256, 0, stream>>>(w, wtp);
        conv_mfma_kernel<<<grid, 256, 0, stream>>>(x, wtp, bias, shp, swp, out);
    } else {
        conv_fallback_kernel<<<grid, 256, 0, stream>>>(x, w, bias, shp, swp, out);
    }
}

// Round 4
// 91.903 us; speedup vs baseline: 3.3231x; 1.0310x over previous
//
#include <hip/hip_runtime.h>
#include <cstddef>

#define BB  32
#define CC  128
#define HH  64
#define WW  64
#define OO  256
#define OHH 32
#define OWW 32
#define YSTR 196   // yr row stride (bf16): 392B -> 2-way banks (free)
#define PSTR 296   // patchT row stride: 288 data + 8 pad; 592B rows, 16B-aligned

typedef __bf16 bf16x8 __attribute__((ext_vector_type(8)));
typedef __bf16 bf16x4 __attribute__((ext_vector_type(4)));
typedef float  f32x4  __attribute__((ext_vector_type(4)));

// ---- weight transform: w[o][c][3][3] f32 -> wt[o][k][c] bf16 (k = kh*3+kw) ----
__global__ void wtrans_bf16_kernel(const float* __restrict__ w, __bf16* __restrict__ wt) {
    int idx = blockIdx.x * 256 + threadIdx.x;          // (o*9 + k)*128 + c
    if (idx >= OO * 9 * CC) return;
    int c    = idx & 127;
    int rest = idx >> 7;
    int k    = rest % 9;
    int o    = rest / 9;
    wt[idx] = (__bf16)w[((size_t)o * CC + c) * 9 + k];
}

// ---- fused bilinear-im2col + bf16 MFMA; grid (b=32, p=32), 256 thr = 4 waves ----
__global__ __launch_bounds__(256, 5)
void conv_mfma_kernel(const float* __restrict__ x, const __bf16* __restrict__ wt,
                      const float* __restrict__ bias, const float* __restrict__ shp,
                      const float* __restrict__ swp, float* __restrict__ out) {
    __shared__ __bf16 yr[32 * YSTR];       // 12544 B  row-interp [c][kh][w]
    __shared__ __bf16 patchT[32 * PSTR];   // 18944 B  B-operand [q][k*32+c]

    const int tid = threadIdx.x;
    const int b   = blockIdx.x;
    const int p   = blockIdx.y;
    const float sh = shp[0];
    const float sw = swp[0];

    const float hpos = (float)p * sh - 1.0f;
    const float hbf  = floorf(hpos);
    const float fh   = hpos - hbf;
    const int   hb   = (int)hbf;

    // ---- bias-only fast path (all sampled rows OOB) ----
    if (hb >= HH || hb <= -4) {
#pragma unroll
        for (int rep = 0; rep < 8; ++rep) {
            int o  = rep * 32 + (tid >> 3);
            int q0 = (tid & 7) << 2;
            float bv = bias[o];
            float4 r; r.x = bv; r.y = bv; r.z = bv; r.w = bv;
            *(float4*)(out + (((size_t)b * OO + o) * OHH + p) * OWW + q0) = r;
        }
        return;
    }

    const int wv = tid >> 6;     // wave -> o block
    const int l  = tid & 63;
    const int lr = l & 15;
    const int lg = l >> 4;
    const int o0 = wv * 64;

    // x-load ownership
    const int cA   = tid >> 4;            // 0..15 (channel within chunk, +16 for i=1)
    const int col4 = (tid & 15) << 2;     // 0..60

    int  hr[4];
    bool rvb[4];
#pragma unroll
    for (int r = 0; r < 4; ++r) {
        hr[r]  = hb + r;
        rvb[r] = (hr[r] >= 0) && (hr[r] < HH);
    }

    // stage-B ownership: c = tid&31, q in {q0, q0+8, q0+16, q0+24}
    const int cB = tid & 31;
    const int q0 = tid >> 5;
    float fwr[4];
    int   wbr[4];
#pragma unroll
    for (int j = 0; j < 4; ++j) {
        float wpos = (float)(q0 + 8 * j) * sw - 1.0f;
        float wbf  = floorf(wpos);
        fwr[j] = wpos - wbf;
        wbr[j] = (int)wbf;
    }

    f32x4 acc[4][2];
#pragma unroll
    for (int ot = 0; ot < 4; ++ot)
#pragma unroll
        for (int qt = 0; qt < 2; ++qt) acc[ot][qt] = (f32x4)0.0f;

    // prefetch + row-interp chunk 0 into bf16 regs (12 VGPR steady)
    bf16x4 y[2][3];
#pragma unroll
    for (int i = 0; i < 2; ++i) {
        const float* xp = x + ((size_t)(b * CC + cA + i * 16) * HH) * WW + col4;
        float4 v[4];
#pragma unroll
        for (int r = 0; r < 4; ++r) {
            float4 t = {0.f, 0.f, 0.f, 0.f};
            if (rvb[r]) t = *(const float4*)(xp + (size_t)hr[r] * WW);
            v[r] = t;
        }
#pragma unroll
        for (int kh = 0; kh < 3; ++kh) {
            bf16x4 t;
            t[0] = (__bf16)(v[kh].x + fh * (v[kh + 1].x - v[kh].x));
            t[1] = (__bf16)(v[kh].y + fh * (v[kh + 1].y - v[kh].y));
            t[2] = (__bf16)(v[kh].z + fh * (v[kh + 1].z - v[kh].z));
            t[3] = (__bf16)(v[kh].w + fh * (v[kh + 1].w - v[kh].w));
            y[i][kh] = t;
        }
    }

    for (int chunk = 0; chunk < 4; ++chunk) {
        const int c0 = chunk * 32;

        // ---- 1. yr write from interp regs ----
#pragma unroll
        for (int i = 0; i < 2; ++i)
#pragma unroll
            for (int kh = 0; kh < 3; ++kh)
                *(bf16x4*)&yr[(cA + i * 16) * YSTR + kh * 64 + col4] = y[i][kh];
        __syncthreads();   // barA: yr ready; prev MFMA's patchT reads drained

        // ---- 2. issue next chunk's x loads (latency hides under stage B) ----
        float4 xv[2][4];
        if (chunk < 3) {
#pragma unroll
            for (int i = 0; i < 2; ++i) {
                const float* xp = x + ((size_t)(b * CC + c0 + 32 + cA + i * 16) * HH) * WW + col4;
#pragma unroll
                for (int r = 0; r < 4; ++r) {
                    float4 t = {0.f, 0.f, 0.f, 0.f};
                    if (rvb[r]) t = *(const float4*)(xp + (size_t)hr[r] * WW);
                    xv[i][r] = t;
                }
            }
        }

        // ---- 3. stage B: col interp yr -> patchT (4 reads serve 3 taps) ----
#pragma unroll
        for (int j = 0; j < 4; ++j) {
            const int   q   = q0 + 8 * j;
            const float fw  = fwr[j];
            const int   wb0 = wbr[j];
            __bf16* pq = &patchT[q * PSTR + cB];
#pragma unroll
            for (int kh = 0; kh < 3; ++kh) {
                const __bf16* yb = &yr[cB * YSTR + kh * 64];
                float s[4];
#pragma unroll
                for (int t = 0; t < 4; ++t) {
                    int w = wb0 + t;
                    s[t] = ((unsigned)w < WW) ? (float)yb[w] : 0.0f;
                }
#pragma unroll
                for (int kw = 0; kw < 3; ++kw)
                    pq[(kh * 3 + kw) * 32] = (__bf16)(s[kw] + fw * (s[kw + 1] - s[kw]));
            }
        }

        // ---- 3b. row-interp next chunk into y regs (after loads drain) ----
        if (chunk < 3) {
#pragma unroll
            for (int i = 0; i < 2; ++i)
#pragma unroll
                for (int kh = 0; kh < 3; ++kh) {
                    bf16x4 t;
                    t[0] = (__bf16)(xv[i][kh].x + fh * (xv[i][kh + 1].x - xv[i][kh].x));
                    t[1] = (__bf16)(xv[i][kh].y + fh * (xv[i][kh + 1].y - xv[i][kh].y));
                    t[2] = (__bf16)(xv[i][kh].z + fh * (xv[i][kh + 1].z - xv[i][kh].z));
                    t[3] = (__bf16)(xv[i][kh].w + fh * (xv[i][kh + 1].w - xv[i][kh].w));
                    y[i][kh] = t;
                }
        }
        __syncthreads();   // barB: patchT ready; yr reads drained

        // ---- 4. MFMA: 9 taps x (4o x 2q) ----
        __builtin_amdgcn_s_setprio(1);
#pragma unroll
        for (int k = 0; k < 9; ++k) {
            const __bf16* wp = wt + ((size_t)(o0 + lr) * 9 + k) * CC + c0 + lg * 8;
            bf16x8 a0 = *(const bf16x8*)(wp + (size_t)0  * 9 * CC);
            bf16x8 a1 = *(const bf16x8*)(wp + (size_t)16 * 9 * CC);
            bf16x8 a2 = *(const bf16x8*)(wp + (size_t)32 * 9 * CC);
            bf16x8 a3 = *(const bf16x8*)(wp + (size_t)48 * 9 * CC);
            bf16x8 b0 = *(const bf16x8*)&patchT[lr * PSTR + k * 32 + lg * 8];
            bf16x8 b1 = *(const bf16x8*)&patchT[(16 + lr) * PSTR + k * 32 + lg * 8];
            acc[0][0] = __builtin_amdgcn_mfma_f32_16x16x32_bf16(a0, b0, acc[0][0], 0, 0, 0);
            acc[0][1] = __builtin_amdgcn_mfma_f32_16x16x32_bf16(a0, b1, acc[0][1], 0, 0, 0);
            acc[1][0] = __builtin_amdgcn_mfma_f32_16x16x32_bf16(a1, b0, acc[1][0], 0, 0, 0);
            acc[1][1] = __builtin_amdgcn_mfma_f32_16x16x32_bf16(a1, b1, acc[1][1], 0, 0, 0);
            acc[2][0] = __builtin_amdgcn_mfma_f32_16x16x32_bf16(a2, b0, acc[2][0], 0, 0, 0);
            acc[2][1] = __builtin_amdgcn_mfma_f32_16x16x32_bf16(a2, b1, acc[2][1], 0, 0, 0);
            acc[3][0] = __builtin_amdgcn_mfma_f32_16x16x32_bf16(a3, b0, acc[3][0], 0, 0, 0);
            acc[3][1] = __builtin_amdgcn_mfma_f32_16x16x32_bf16(a3, b1, acc[3][1], 0, 0, 0);
        }
        __builtin_amdgcn_s_setprio(0);
        // patchT overwrite fenced by next barA; yr overwrite fenced by barB.
    }

    // ---- epilogue: + bias, store (C/D: col=lane&15, row=(lane>>4)*4+reg) ----
#pragma unroll
    for (int ot = 0; ot < 4; ++ot) {
#pragma unroll
        for (int r = 0; r < 4; ++r) {
            int o = o0 + ot * 16 + lg * 4 + r;
            float bv = bias[o];
            float* op = out + (((size_t)b * OO + o) * OHH + p) * OWW;
            op[lr]      = acc[ot][0][r] + bv;
            op[16 + lr] = acc[ot][1][r] + bv;
        }
    }
}

// ---- fp32 fallback (no workspace) ----
__global__ __launch_bounds__(256)
void conv_fallback_kernel(const float* __restrict__ x, const float* __restrict__ w,
                          const float* __restrict__ bias, const float* __restrict__ shp,
                          const float* __restrict__ swp, float* __restrict__ out) {
    __shared__ __align__(16) float xr[4][WW];
    __shared__ __align__(16) float patch[9][OWW];
    const int tid = threadIdx.x;
    const int p = blockIdx.y;
    const int b = blockIdx.x;
    const float sh = shp[0];
    const float sw = swp[0];
    const float hpos = (float)p * sh - 1.0f;
    const float hbf  = floorf(hpos);
    const float fh   = hpos - hbf;
    const int   hb   = (int)hbf;
    const int og = tid & 63;
    const int qg = tid >> 6;
    const int o0 = og * 4;
    const int q0 = qg * 8;
    const int rr   = tid >> 6;
    const int colc = tid & 63;
    const int rowg = hb + rr;
    const bool rv = (rowg >= 0) && (rowg < HH);
    float acc[4][8];
#pragma unroll
    for (int i = 0; i < 4; ++i)
#pragma unroll
        for (int j = 0; j < 8; ++j) acc[i][j] = 0.0f;
    for (int c = 0; c < CC; ++c) {
        float vv = 0.0f;
        if (rv) vv = x[(((size_t)b * CC + c) * HH + rowg) * WW + colc];
        xr[rr][colc] = vv;
        __syncthreads();
        for (int it = tid; it < 9 * OWW; it += 256) {
            int k = it >> 5; int q = it & 31;
            int kh = k / 3;  int kw = k - kh * 3;
            float wpos = (float)q * sw - 1.0f + (float)kw;
            float wbf = floorf(wpos);
            float fw = wpos - wbf;
            int wb = (int)wbf;
            float x00 = 0, x01 = 0, x10 = 0, x11 = 0;
            if (wb >= 0 && wb < WW)         { x00 = xr[kh][wb];     x10 = xr[kh + 1][wb]; }
            if (wb + 1 >= 0 && wb + 1 < WW) { x01 = xr[kh][wb + 1]; x11 = xr[kh + 1][wb + 1]; }
            float top = x00 * (1.0f - fw) + x01 * fw;
            float bot = x10 * (1.0f - fw) + x11 * fw;
            patch[k][q] = top * (1.0f - fh) + bot * fh;
        }
        __syncthreads();
        const float4* pv = (const float4*)&patch[0][0];
#pragma unroll
        for (int k = 0; k < 9; ++k) {
            const float* wb_ = w + (size_t)o0 * (CC * 9) + c * 9 + k;
            float wvv[4] = {wb_[0], wb_[1 * CC * 9], wb_[2 * CC * 9], wb_[3 * CC * 9]};
            float4 pa = pv[k * 8 + (q0 >> 2)];
            float4 pb = pv[k * 8 + (q0 >> 2) + 1];
#pragma unroll
            for (int oo2 = 0; oo2 < 4; ++oo2) {
                acc[oo2][0] += wvv[oo2] * pa.x; acc[oo2][1] += wvv[oo2] * pa.y;
                acc[oo2][2] += wvv[oo2] * pa.z; acc[oo2][3] += wvv[oo2] * pa.w;
                acc[oo2][4] += wvv[oo2] * pb.x; acc[oo2][5] += wvv[oo2] * pb.y;
                acc[oo2][6] += wvv[oo2] * pb.z; acc[oo2][7] += wvv[oo2] * pb.w;
            }
        }
    }
    float4 bv = ((const float4*)bias)[og];
    float bvv[4] = {bv.x, bv.y, bv.z, bv.w};
#pragma unroll
    for (int oo2 = 0; oo2 < 4; ++oo2) {
        size_t off = (((size_t)b * OO + o0 + oo2) * OHH + p) * OWW + q0;
        float4 r0, r1;
        r0.x = acc[oo2][0] + bvv[oo2]; r0.y = acc[oo2][1] + bvv[oo2];
        r0.z = acc[oo2][2] + bvv[oo2]; r0.w = acc[oo2][3] + bvv[oo2];
        r1.x = acc[oo2][4] + bvv[oo2]; r1.y = acc[oo2][5] + bvv[oo2];
        r1.z = acc[oo2][6] + bvv[oo2]; r1.w = acc[oo2][7] + bvv[oo2];
        *(float4*)(out + off)     = r0;
        *(float4*)(out + off + 4) = r1;
    }
}

extern "C" void kernel_launch(void* const* d_in, const int* in_sizes, int n_in,
                              void* d_out, int out_size, void* d_ws, size_t ws_size,
                              hipStream_t stream) {
    const float* x    = (const float*)d_in[0];
    const float* w    = (const float*)d_in[1];
    const float* bias = (const float*)d_in[2];
    const float* shp  = (const float*)d_in[3];
    const float* swp  = (const float*)d_in[4];
    float* out = (float*)d_out;

    const size_t wt_bytes = (size_t)OO * 9 * CC * sizeof(__bf16);   // 576 KB
    dim3 grid(BB, OHH);
    if (ws_size >= wt_bytes) {
        __bf16* wtp = (__bf16*)d_ws;
        int n = OO * 9 * CC;
        wtrans_bf16_kernel<<<(n + 255) / 256, 256, 0, stream>>>(w, wtp);
        conv_mfma_kernel<<<grid, 256, 0, stream>>>(x, wtp, bias, shp, swp, out);
    } else {
        conv_fallback_kernel<<<grid, 256, 0, stream>>>(x, w, bias, shp, swp, out);
    }
}